// Round 4
// baseline (945.719 us; speedup 1.0000x reference)
//
#include <hip/hip_runtime.h>
#include <math.h>

#define DIM 16384
#define NTH 512

typedef float v2f __attribute__((ext_vector_type(2)));

// wire w <-> bit position (13-w). XOR bank-fold swizzle (bijective, XOR-linear).
__host__ __device__ constexpr int cswz(int i) {
  return i ^ ((i >> 4) & 15) ^ ((i >> 8) & 15) ^ ((i >> 12) & 3);
}

// local wires per pass (local bit b <-> wire LW[p][b])
constexpr int LW[8][5] = {
  {13, 12, 11, 10, 0},   // WA
  {10, 9, 8, 7, 6},      // WB
  {6, 5, 4, 3, 2},       // WC
  {2, 1, 0, 3, 4},       // WD (3,4 pad)
  {12, 13, 0, 1, 2},     // WE
  {2, 3, 4, 5, 6},       // WF
  {6, 7, 8, 9, 10},      // WG
  {10, 11, 12, 13, 9},   // WH (9 pad)
};
// tid bit k -> bit position PMAP[p][k]
constexpr int PMAP[8][9] = {
  {4, 5, 6, 7, 8, 9, 10, 11, 12},
  {0, 1, 2, 11, 8, 9, 10, 12, 13},
  {0, 1, 2, 3, 4, 5, 6, 12, 13},
  {0, 1, 2, 3, 4, 5, 6, 7, 8},
  {2, 3, 4, 5, 6, 7, 8, 9, 10},
  {0, 1, 2, 3, 4, 5, 6, 12, 13},
  {0, 1, 2, 11, 8, 9, 10, 12, 13},
  {5, 6, 7, 8, 9, 10, 11, 12, 13},
};
constexpr int NG[8] = {9, 8, 8, 3, 9, 8, 8, 3};
// {kind(0=RY,1=CRX), bitA(RY tgt / CRX ctrl), bitB(CRX tgt), cs index (layer-rel)}
constexpr int GATES[8][9][4] = {
  {{0,4,0,0},{0,3,0,10},{0,2,0,11},{0,1,0,12},{0,0,0,13},{1,0,4,14},{1,1,0,15},{1,2,1,16},{1,3,2,17}},
  {{0,4,0,6},{0,3,0,7},{0,2,0,8},{0,1,0,9},{1,1,0,18},{1,2,1,19},{1,3,2,20},{1,4,3,21},{0,0,0,0}},
  {{0,4,0,2},{0,3,0,3},{0,2,0,4},{0,1,0,5},{1,1,0,22},{1,2,1,23},{1,3,2,24},{1,4,3,25},{0,0,0,0}},
  {{0,1,0,1},{1,1,0,26},{1,2,1,27},{0,0,0,0},{0,0,0,0},{0,0,0,0},{0,0,0,0},{0,0,0,0},{0,0,0,0}},
  {{0,2,0,28},{0,3,0,29},{0,4,0,30},{0,0,0,40},{0,1,0,41},{1,1,0,42},{1,2,1,43},{1,3,2,44},{1,4,3,45}},
  {{0,1,0,31},{0,2,0,32},{0,3,0,33},{0,4,0,34},{1,1,0,46},{1,2,1,47},{1,3,2,48},{1,4,3,49},{0,0,0,0}},
  {{0,1,0,35},{0,2,0,36},{0,3,0,37},{0,4,0,38},{1,1,0,50},{1,2,1,51},{1,3,2,52},{1,4,3,53},{0,0,0,0}},
  {{0,1,0,39},{1,1,0,54},{1,2,1,55},{0,0,0,0},{0,0,0,0},{0,0,0,0},{0,0,0,0},{0,0,0,0},{0,0,0,0}},
};

__host__ __device__ constexpr int offcube(int p, int j) {
  int o = 0;
  for (int b = 0; b < 5; ++b)
    if ((j >> b) & 1) o |= 1 << (13 - LW[p][b]);
  return o;
}

// MODE: 0 = gather+gates+scatter, 1 = |0>-init+gates+scatter, 2 = gather+gates (no scatter)
template <int PID, int MODE>
__device__ __forceinline__ void run_pass(v2f* __restrict__ S, const v2f* __restrict__ CS,
                                         int lb, int tid, v2f* __restrict__ a) {
  int base = 0;
#pragma unroll
  for (int k = 0; k < 9; ++k) base |= ((tid >> k) & 1) << PMAP[PID][k];
  const int sb = cswz(base);
  if (MODE == 1) {
#pragma unroll
    for (int j = 0; j < 32; ++j) a[j] = v2f{0.f, 0.f};
    if (tid == 0) a[0] = v2f{1.f, 0.f};
  } else {
#pragma unroll
    for (int j = 0; j < 32; ++j) a[j] = S[sb ^ cswz(offcube(PID, j))];
  }
#pragma unroll
  for (int g = 0; g < NG[PID]; ++g) {
    const v2f cs2 = CS[lb + GATES[PID][g][3]];
    const float c = cs2.x, s = cs2.y;
    if (GATES[PID][g][0] == 0) {
      const int tb = GATES[PID][g][1];
#pragma unroll
      for (int j = 0; j < 32; ++j)
        if (!((j >> tb) & 1)) {
          const int j2 = j | (1 << tb);
          const v2f a0 = a[j], a1 = a[j2];
          a[j]  = c * a0 - s * a1;
          a[j2] = s * a0 + c * a1;
        }
    } else {
      const int bc = GATES[PID][g][1], bt = GATES[PID][g][2];
#pragma unroll
      for (int j = 0; j < 32; ++j)
        if (((j >> bc) & 1) && !((j >> bt) & 1)) {
          const int j2 = j | (1 << bt);
          const v2f t0 = a[j], t1 = a[j2];
          a[j]  = c * t0 + s * v2f{t1.y, -t1.x};
          a[j2] = c * t1 + s * v2f{t0.y, -t0.x};
        }
    }
  }
  if (MODE != 2) {
#pragma unroll
    for (int j = 0; j < 32; ++j) S[sb ^ cswz(offcube(PID, j))] = a[j];
  }
  __syncthreads();
}

// one full 112-gate sim; a[] ends holding the final state in the WH cube mapping
__device__ __forceinline__ void run_sim(v2f* __restrict__ S, const v2f* __restrict__ CS,
                                        int tid, v2f* __restrict__ a,
                                        const v2f* __restrict__ basev, int own_sb,
                                        bool initzero) {
  if (initzero) {
    run_pass<0, 1>(S, CS, 0, tid, a);
  } else {
#pragma unroll
    for (int j = 0; j < 32; ++j) S[own_sb ^ cswz(offcube(7, j))] = basev[j];
    __syncthreads();
    run_pass<0, 0>(S, CS, 0, tid, a);
  }
  run_pass<1, 0>(S, CS, 0, tid, a);
  run_pass<2, 0>(S, CS, 0, tid, a);
  run_pass<3, 0>(S, CS, 0, tid, a);
  run_pass<4, 0>(S, CS, 0, tid, a);
  run_pass<5, 0>(S, CS, 0, tid, a);
  run_pass<6, 0>(S, CS, 0, tid, a);
  run_pass<7, 0>(S, CS, 0, tid, a);
  run_pass<0, 0>(S, CS, 56, tid, a);
  run_pass<1, 0>(S, CS, 56, tid, a);
  run_pass<2, 0>(S, CS, 56, tid, a);
  run_pass<3, 0>(S, CS, 56, tid, a);
  run_pass<4, 0>(S, CS, 56, tid, a);
  run_pass<5, 0>(S, CS, 56, tid, a);
  run_pass<6, 0>(S, CS, 56, tid, a);
  run_pass<7, 2>(S, CS, 56, tid, a);  // final: keep in registers
}

__device__ __forceinline__ float block_sum(float v, int tid, float* red) {
#pragma unroll
  for (int off = 32; off; off >>= 1) v += __shfl_xor(v, off);
  if ((tid & 63) == 0) red[tid >> 6] = v;
  __syncthreads();
  float tot = 0.f;
#pragma unroll
  for (int w = 0; w < 8; ++w) tot += red[w];
  __syncthreads();
  return tot;
}

__global__ void
__attribute__((amdgpu_flat_work_group_size(512, 512)))
__attribute__((amdgpu_waves_per_eu(2, 2)))
qts_kernel(
    const float* __restrict__ x, const float* __restrict__ Win,
    const float* __restrict__ bin, const float* __restrict__ mix,
    const float* __restrict__ poly, const float* __restrict__ Wout,
    const float* __restrict__ bout, float* __restrict__ out) {
  extern __shared__ v2f S[];           // DIM state + 448 cos/sin + reduce scratch
  v2f* CSall = S + DIM;
  float* red = (float*)(S + DIM + 448);
  const int tid = threadIdx.x;
  const int b = blockIdx.x;

  // angles for all 4 timesteps at once: theta = sigmoid(x@Win+bin); store (cos,sin)(theta/2)
  if (tid < 448) {
    float z = bin[tid];
    const float x0 = x[b * 4 + 0], x1 = x[b * 4 + 1], x2 = x[b * 4 + 2], x3 = x[b * 4 + 3];
    z += x0 * Win[tid] + x1 * Win[448 + tid] + x2 * Win[896 + tid] + x3 * Win[1344 + tid];
    const float th = 1.f / (1.f + expf(-z));
    float sn, cc;
    sincosf(0.5f * th, &sn, &cc);
    CSall[tid] = v2f{cc, sn};
  }
  __syncthreads();

  int ownbase = 0;
#pragma unroll
  for (int k = 0; k < 9; ++k) ownbase |= ((tid >> k) & 1) << PMAP[7][k];
  const int own_sb = cswz(ownbase);

  const float p0 = poly[0], p1 = poly[1], p2 = poly[2];

  v2f a[32], acc[32], basev[32];
  float alpha;

  // ---- degree 0 (base = |0>) ----
#pragma unroll
  for (int j = 0; j < 32; ++j) acc[j] = v2f{0.f, 0.f};
  for (int t = 0; t < 4; ++t) {
    run_sim(S, CSall + t * 112, tid, a, basev, own_sb, true);
    const float mc = mix[t];
#pragma unroll
    for (int j = 0; j < 32; ++j) acc[j] += mc * a[j];
  }
  {
    float part = 0.f;
#pragma unroll
    for (int j = 0; j < 32; ++j) part += acc[j].x * acc[j].x + acc[j].y * acc[j].y;
    const float tot = block_sum(part, tid, red);
    const float nu = sqrtf(tot) + 1e-9f;
    const float inv = 1.f / nu;
    alpha = p0 * nu;                   // res-so-far == alpha * basev
#pragma unroll
    for (int j = 0; j < 32; ++j) { basev[j] = inv * acc[j]; acc[j] = v2f{0.f, 0.f}; }
  }

  // ---- degree 1 ----
  for (int t = 0; t < 4; ++t) {
    run_sim(S, CSall + t * 112, tid, a, basev, own_sb, false);
    const float mc = mix[t];
#pragma unroll
    for (int j = 0; j < 32; ++j) acc[j] += mc * a[j];
  }
  {
    float part = 0.f;
#pragma unroll
    for (int j = 0; j < 32; ++j) part += acc[j].x * acc[j].x + acc[j].y * acc[j].y;
    const float tot = block_sum(part, tid, red);
    const float nu = sqrtf(tot) + 1e-9f;
    const float inv = 1.f / nu;
#pragma unroll
    for (int j = 0; j < 32; ++j) {
      const v2f tmp = acc[j];
      acc[j] = alpha * basev[j] + p1 * tmp;  // acc becomes res accumulator
      basev[j] = inv * tmp;
    }
  }

  // ---- degree 2 (accumulate straight into res) ----
  for (int t = 0; t < 4; ++t) {
    run_sim(S, CSall + t * 112, tid, a, basev, own_sb, false);
    const float mc = p2 * mix[t];
#pragma unroll
    for (int j = 0; j < 32; ++j) acc[j] += mc * a[j];
  }

  // ---- expz per wire + total norm from res (= acc), then tiny GEMV ----
  float part[15];
#pragma unroll
  for (int v = 0; v < 15; ++v) part[v] = 0.f;
#pragma unroll
  for (int j = 0; j < 32; ++j) {
    const int idx = ownbase | offcube(7, j);
    const float p = acc[j].x * acc[j].x + acc[j].y * acc[j].y;
    part[14] += p;
#pragma unroll
    for (int w = 0; w < 14; ++w) part[w] += ((idx >> (13 - w)) & 1) ? -p : p;
  }
  __syncthreads();
#pragma unroll
  for (int v = 0; v < 15; ++v) {
    float xv = part[v];
#pragma unroll
    for (int off = 32; off; off >>= 1) xv += __shfl_xor(xv, off);
    if ((tid & 63) == 0) red[(tid >> 6) * 15 + v] = xv;
  }
  __syncthreads();
  if (tid < 15) {
    float tot = 0.f;
#pragma unroll
    for (int w = 0; w < 8; ++w) tot += red[w * 15 + tid];
    red[128 + tid] = tot;
  }
  __syncthreads();
  if (tid < 2) {
    const float nrm = sqrtf(red[128 + 14]) + 1e-9f;
    const float iv = 1.f / (nrm * nrm);
    float o = bout[tid];
#pragma unroll
    for (int w = 0; w < 14; ++w) o += red[128 + w] * iv * Wout[w * 2 + tid];
    out[b * 2 + tid] = o;
  }
}

extern "C" void kernel_launch(void* const* d_in, const int* in_sizes, int n_in,
                              void* d_out, int out_size, void* d_ws, size_t ws_size,
                              hipStream_t stream) {
  const float* x    = (const float*)d_in[0];
  const float* Win  = (const float*)d_in[1];
  const float* bin  = (const float*)d_in[2];
  const float* mix  = (const float*)d_in[3];
  const float* poly = (const float*)d_in[4];
  const float* Wout = (const float*)d_in[5];
  const float* bout = (const float*)d_in[6];
  float* out = (float*)d_out;

  const size_t shmem = (size_t)DIM * sizeof(v2f) + 448 * sizeof(v2f) + 1024;  // 135680 B
  hipFuncSetAttribute((const void*)qts_kernel,
                      hipFuncAttributeMaxDynamicSharedMemorySize, (int)shmem);
  qts_kernel<<<256, NTH, shmem, stream>>>(x, Win, bin, mix, poly, Wout, bout, out);
}